// Round 1
// baseline (126.658 us; speedup 1.0000x reference)
//
#include <hip/hip_runtime.h>
#include <hip/hip_bf16.h>

typedef __attribute__((ext_vector_type(8))) short short8;
typedef __attribute__((ext_vector_type(4))) float floatx4;

#define NROWS 4096
#define NHALF 2048
#define DDIM  128
#define LDST  136                 // LDS row stride in ushorts (128 + 8 pad -> 272B, 2-way = free)
#define SQRT_SCALE 2.6857914f     // sqrt(1/(0.2*ln2)) ; dot of stored z == (sim/T)*log2(e)
#define LN2 0.69314718056f

// ws float layout: [0]=loss acc, [1]=all_num, [2]=k_loss completion counter,
// rowsum [64, 64+16384), diag [16448, +16384), pos [32832, +16384)
#define WS_ROWSUM_OFF 64
#define WS_DIAG_OFF   16448
#define WS_POS_OFF    32832
#define WS_Z_BYTE_OFF 196864      // (64+3*16384)*4, 16B aligned

__device__ inline unsigned short f2bf(float f) {
    unsigned u = __builtin_bit_cast(unsigned, f);
    u += 0x7fffu + ((u >> 16) & 1u);          // RNE
    return (unsigned short)(u >> 16);
}

// ---------------- kernel 1: normalize + scale + cast to bf16; zero accumulators; all_num ----
__global__ __launch_bounds__(256) void k_norm(const float* __restrict__ emb_i,
                                              const float* __restrict__ emb_j,
                                              const float* __restrict__ jv,
                                              float* __restrict__ wsf,
                                              unsigned short* __restrict__ z) {
    int bx = blockIdx.x, tid = threadIdx.x;
    if (bx == 4096) {                         // all_num = sum(joint_valid)
        __shared__ float sred[256];
        float s = 0.f;
        #pragma unroll
        for (int i = 0; i < 8; ++i) s += jv[tid + 256 * i];
        sred[tid] = s; __syncthreads();
        for (int off = 128; off > 0; off >>= 1) {
            if (tid < off) sred[tid] += sred[tid + off];
            __syncthreads();
        }
        if (tid == 0) wsf[1] = sred[0];
        return;
    }
    int gid = bx * 256 + tid;                 // zero loss acc + counter + rowsum (ws poisoned each call)
    if (gid == 0) { wsf[0] = 0.f; *(unsigned*)&wsf[2] = 0u; }
    if (gid >= WS_ROWSUM_OFF && gid < WS_ROWSUM_OFF + 16384) wsf[gid] = 0.f;

    int wave = tid >> 6, lane = tid & 63;
    int r = bx * 4 + wave;                    // global row 0..16383
    int l = r >> 12, n = r & 4095;
    const float* src = (n < NHALF) ? (emb_i + ((size_t)l * NHALF + n) * DDIM)
                                   : (emb_j + ((size_t)l * NHALF + (n - NHALF)) * DDIM);
    float2 v = *(const float2*)(src + lane * 2);
    float ss = v.x * v.x + v.y * v.y;
    #pragma unroll
    for (int off = 1; off < 64; off <<= 1) ss += __shfl_xor(ss, off);
    float inv = SQRT_SCALE / fmaxf(sqrtf(ss), 1e-12f);
    unsigned pack = ((unsigned)f2bf(v.y * inv) << 16) | (unsigned)f2bf(v.x * inv);
    *(unsigned*)(z + (size_t)r * DDIM + lane * 2) = pack;
}

// ---------------- kernel 2: SYMMETRIC fused sim GEMM + exp2 row/col sums + diag/pos ---------
// sim is symmetric: compute only upper-triangle 256x256 tiles (I<=J), 136/l -> 544 blocks.
// Off-diag tiles scatter exp2 sums to BOTH row range (rsum over cols) and col range
// (per-subtile reduce over the 16 rows -> csum, LDS-combined across waves, 1 atomic/col).
// Halves exp2 (67M->36M), MFMA, and LDS staging vs. the full-matrix version.
// 4 waves, 64 rows/wave; 2 col-stages of 128 (LDS 34KB); 2 blocks/CU.
__global__ __launch_bounds__(256, 2) void k_sim(const unsigned short* __restrict__ z,
                                                float* __restrict__ rowsum,
                                                float* __restrict__ diag,
                                                float* __restrict__ pos) {
    __shared__ __align__(16) unsigned short lds[128 * LDST];
    int bx = blockIdx.x, tid = threadIdx.x;
    int l = bx & 3, idx = bx >> 2;            // idx in [0,136): idx = J*(J+1)/2 + I, I<=J
    int J = (int)((sqrtf(8.f * (float)idx + 1.f) - 1.f) * 0.5f);
    while ((J + 1) * (J + 2) / 2 <= idx) ++J; // guard fp rounding
    while (J * (J + 1) / 2 > idx) --J;
    int I = idx - J * (J + 1) / 2;
    int wave = tid >> 6, lane = tid & 63, m = lane & 15, quad = lane >> 4;
    const unsigned short* zl = z + (size_t)l * NROWS * DDIM;
    int l4 = l * NROWS;
    int wr0 = I * 256 + wave * 64;

    short8 a[4][4];                           // 4 row-subtiles x 4 k-steps, resident in VGPRs
    #pragma unroll
    for (int rs = 0; rs < 4; ++rs) {
        const unsigned short* p = zl + (size_t)(wr0 + rs * 16 + m) * DDIM + quad * 8;
        #pragma unroll
        for (int kk = 0; kk < 4; ++kk) a[rs][kk] = *(const short8*)(p + kk * 32);
    }
    floatx4 rsum[4];
    #pragma unroll
    for (int rs = 0; rs < 4; ++rs) rsum[rs] = (floatx4){0.f, 0.f, 0.f, 0.f};
    float csum[16];                           // per-lane col-sum partial, col = gcs*16 + m
    #pragma unroll
    for (int g = 0; g < 16; ++g) csum[g] = 0.f;

    #pragma unroll                            // MUST unroll: csum[] indexed by stg (rule #20)
    for (int stg = 0; stg < 2; ++stg) {       // 2 x 128-col LDS tiles (256 cols per block)
        int cg0 = J * 256 + stg * 128;
        __syncthreads();
        #pragma unroll
        for (int i = 0; i < 8; ++i) {         // stage 128x128 bf16 (32KB), 16B chunks
            int chunk = tid + 256 * i;
            int col = chunk >> 4, off = chunk & 15;
            uint4 d = *(const uint4*)(zl + (size_t)(cg0 + col) * DDIM + off * 8);
            *(uint4*)&lds[col * LDST + off * 8] = d;
        }
        __syncthreads();
        #pragma unroll
        for (int cs = 0; cs < 8; ++cs) {      // 16-col subtiles
            int ct = cg0 + cs * 16;           // tile column base (wave-uniform)
            const unsigned short* lp = &lds[(cs * 16 + m) * LDST + quad * 8];
            short8 b0 = *(const short8*)(lp);
            short8 b1 = *(const short8*)(lp + 32);
            short8 b2 = *(const short8*)(lp + 64);
            short8 b3 = *(const short8*)(lp + 96);
            #pragma unroll
            for (int rs = 0; rs < 4; ++rs) {
                floatx4 acc = (floatx4){0.f, 0.f, 0.f, 0.f};
                acc = __builtin_amdgcn_mfma_f32_16x16x32_bf16(a[rs][0], b0, acc, 0, 0, 0);
                acc = __builtin_amdgcn_mfma_f32_16x16x32_bf16(a[rs][1], b1, acc, 0, 0, 0);
                acc = __builtin_amdgcn_mfma_f32_16x16x32_bf16(a[rs][2], b2, acc, 0, 0, 0);
                acc = __builtin_amdgcn_mfma_f32_16x16x32_bf16(a[rs][3], b3, acc, 0, 0, 0);
                int rowbase = wr0 + rs * 16;
                bool isdiag = (ct == rowbase);          // only possible when I==J
                bool ispos  = (ct == rowbase + 2048);   // only possible when J==I+8
                if (isdiag || ispos) {        // rare, wave-uniform branch
                    int c = m - (quad << 2);  // lane holds (row=rowbase+m) iff quad*4+c == m
                    if (c >= 0 && c < 4) {
                        float v = acc[c];
                        if (isdiag) diag[l4 + rowbase + m] = v;
                        else {                // sim[r, r+2048]; pos is symmetric across halves
                            pos[l4 + rowbase + m] = v;
                            pos[l4 + rowbase + m + NHALF] = v;
                        }
                    }
                }
                float t = 0.f;
                #pragma unroll
                for (int c = 0; c < 4; ++c) {
                    float e = __builtin_amdgcn_exp2f(acc[c]);
                    rsum[rs][c] += e;
                    t += e;                   // sum over this lane's 4 rows
                }
                csum[stg * 8 + cs] += t;      // accumulate col partial across rs
            }
        }
    }
    // row side: reduce across the 16 column-lanes (bits 0..3 of lane)
    #pragma unroll
    for (int off = 1; off < 16; off <<= 1)
        #pragma unroll
        for (int rs = 0; rs < 4; ++rs)
            #pragma unroll
            for (int c = 0; c < 4; ++c)
                rsum[rs][c] += __shfl_xor(rsum[rs][c], off);
    if (m == 0) {                             // lanes 0,16,32,48: rows wr0 + rs*16 + quad*4 + c
        #pragma unroll
        for (int rs = 0; rs < 4; ++rs)
            #pragma unroll
            for (int c = 0; c < 4; ++c) {
                int rg = wr0 + rs * 16 + quad * 4 + c;
                atomicAdd(&rowsum[l4 + rg], rsum[rs][c]);
            }
    }
    // col side (transpose contribution), off-diagonal tiles only — block-uniform branch
    if (I != J) {
        __syncthreads();                      // LDS tile dead; reuse as float reduce buffer
        float* cred = (float*)lds;            // [4 waves][256 cols]
        #pragma unroll
        for (int g = 0; g < 16; ++g) {        // finish reduce over the 16 rows (lane bits 4,5)
            float v = csum[g];
            v += __shfl_xor(v, 16);
            v += __shfl_xor(v, 32);
            if (quad == 0) cred[wave * 256 + g * 16 + m] = v;
        }
        __syncthreads();
        float s = cred[tid] + cred[tid + 256] + cred[tid + 512] + cred[tid + 768];
        atomicAdd(&rowsum[l4 + J * 256 + tid], s);  // 256 atomics/block (LDS pre-reduced)
    }
}

// ---------------- kernel 3: per-row loss; last block finishes the scalar (no k_final) ------
__global__ __launch_bounds__(256) void k_loss(const float* __restrict__ jv,
                                              const float* __restrict__ rowsum,
                                              const float* __restrict__ diag,
                                              const float* __restrict__ pos,
                                              float* __restrict__ wsf,
                                              float* __restrict__ out) {
    __shared__ float sred[256];
    int tid = threadIdx.x;
    int r = blockIdx.x * 256 + tid;           // 64 blocks x 256 = 16384 rows
    int n = r & 4095;
    float denom = rowsum[r] - __builtin_amdgcn_exp2f(diag[r]);  // exact: same fp32 value
    float contrib = LN2 * (__builtin_amdgcn_logf(denom) - pos[r]); // logf = v_log_f32 = log2
    float local = contrib * jv[n & (NHALF - 1)];
    sred[tid] = local; __syncthreads();
    for (int off = 128; off > 0; off >>= 1) {
        if (tid < off) sred[tid] += sred[tid + off];
        __syncthreads();
    }
    if (tid == 0) {
        atomicAdd(&wsf[0], sred[0]);
        __threadfence();                      // order loss-add before counter-add
        unsigned c = atomicAdd((unsigned*)&wsf[2], 1u);
        if (c == 63) {                        // 64th (last) block: finalize
            float tot = atomicAdd(&wsf[0], 0.f);   // device-scope coherent read
            out[0] = tot / (2.f * wsf[1]);
        }
    }
}

extern "C" void kernel_launch(void* const* d_in, const int* in_sizes, int n_in,
                              void* d_out, int out_size, void* d_ws, size_t ws_size,
                              hipStream_t stream) {
    const float* emb_i = (const float*)d_in[0];
    const float* emb_j = (const float*)d_in[1];
    const float* jv    = (const float*)d_in[2];
    float* wsf    = (float*)d_ws;
    float* rowsum = wsf + WS_ROWSUM_OFF;
    float* diag   = wsf + WS_DIAG_OFF;
    float* pos    = wsf + WS_POS_OFF;
    unsigned short* z = (unsigned short*)((char*)d_ws + WS_Z_BYTE_OFF);
    float* out = (float*)d_out;

    k_norm <<<4097, 256, 0, stream>>>(emb_i, emb_j, jv, wsf, z);
    k_sim  <<<544,  256, 0, stream>>>(z, rowsum, diag, pos);   // 4 l x 136 upper-tri tiles
    k_loss <<<64,   256, 0, stream>>>(jv, rowsum, diag, pos, wsf, out);
}

// Round 2
// 106.730 us; speedup vs baseline: 1.1867x; 1.1867x over previous
//
#include <hip/hip_runtime.h>
#include <hip/hip_bf16.h>

typedef __attribute__((ext_vector_type(8))) short short8;
typedef __attribute__((ext_vector_type(4))) float floatx4;

#define NROWS 4096
#define NHALF 2048
#define DDIM  128
#define LDST  136                 // LDS row stride in ushorts (128 + 8 pad -> 272B, 2-way = free)
#define SQRT_SCALE 2.6857914f     // sqrt(1/(0.2*ln2)) ; dot of stored z == (sim/T)*log2(e)
#define LN2 0.69314718056f

// ws float layout: [0]=loss acc, [1]=all_num, [2]=k_loss completion counter,
// rowsum [64, 64+16384), diag [16448, +16384), pos [32832, +16384)
#define WS_ROWSUM_OFF 64
#define WS_DIAG_OFF   16448
#define WS_POS_OFF    32832
#define WS_Z_BYTE_OFF 196864      // (64+3*16384)*4, 16B aligned

__device__ inline unsigned short f2bf(float f) {
    unsigned u = __builtin_bit_cast(unsigned, f);
    u += 0x7fffu + ((u >> 16) & 1u);          // RNE
    return (unsigned short)(u >> 16);
}

// ---------------- kernel 1: normalize + scale + cast to bf16; zero accumulators; all_num ----
__global__ __launch_bounds__(256) void k_norm(const float* __restrict__ emb_i,
                                              const float* __restrict__ emb_j,
                                              const float* __restrict__ jv,
                                              float* __restrict__ wsf,
                                              unsigned short* __restrict__ z) {
    int bx = blockIdx.x, tid = threadIdx.x;
    if (bx == 4096) {                         // all_num = sum(joint_valid)
        __shared__ float sred[256];
        float s = 0.f;
        #pragma unroll
        for (int i = 0; i < 8; ++i) s += jv[tid + 256 * i];
        sred[tid] = s; __syncthreads();
        for (int off = 128; off > 0; off >>= 1) {
            if (tid < off) sred[tid] += sred[tid + off];
            __syncthreads();
        }
        if (tid == 0) wsf[1] = sred[0];
        return;
    }
    int gid = bx * 256 + tid;                 // zero loss acc + counter + rowsum (ws poisoned each call)
    if (gid == 0) { wsf[0] = 0.f; *(unsigned*)&wsf[2] = 0u; }
    if (gid >= WS_ROWSUM_OFF && gid < WS_ROWSUM_OFF + 16384) wsf[gid] = 0.f;

    int wave = tid >> 6, lane = tid & 63;
    int r = bx * 4 + wave;                    // global row 0..16383
    int l = r >> 12, n = r & 4095;
    const float* src = (n < NHALF) ? (emb_i + ((size_t)l * NHALF + n) * DDIM)
                                   : (emb_j + ((size_t)l * NHALF + (n - NHALF)) * DDIM);
    float2 v = *(const float2*)(src + lane * 2);
    float ss = v.x * v.x + v.y * v.y;
    #pragma unroll
    for (int off = 1; off < 64; off <<= 1) ss += __shfl_xor(ss, off);
    float inv = SQRT_SCALE / fmaxf(sqrtf(ss), 1e-12f);
    unsigned pack = ((unsigned)f2bf(v.y * inv) << 16) | (unsigned)f2bf(v.x * inv);
    *(unsigned*)(z + (size_t)r * DDIM + lane * 2) = pack;
}

// ---------------- kernel 2: SYMMETRIC fused sim GEMM + exp2 row/col sums + diag/pos ---------
// sim is symmetric: compute only upper-triangle 256x256 tiles (I<=J), 136/l -> 544 blocks.
// Off-diag tiles scatter exp2 sums to BOTH row range (rsum over cols) and col range
// (per-subtile reduce over the 16 rows -> csum, LDS-combined across waves, 1 atomic/col).
// NOTE: no min-waves clause — live state is ~112 VGPRs (a=64, rsum=16, csum=16, b=16);
// a 128-VGPR cap (launch_bounds(256,2)) forced scratch spills: 75MB WRITE_SIZE, 63us (R1).
__global__ __launch_bounds__(256) void k_sim(const unsigned short* __restrict__ z,
                                             float* __restrict__ rowsum,
                                             float* __restrict__ diag,
                                             float* __restrict__ pos) {
    __shared__ __align__(16) unsigned short lds[128 * LDST];
    int bx = blockIdx.x, tid = threadIdx.x;
    int l = bx & 3, idx = bx >> 2;            // idx in [0,136): idx = J*(J+1)/2 + I, I<=J
    int J = (int)((sqrtf(8.f * (float)idx + 1.f) - 1.f) * 0.5f);
    while ((J + 1) * (J + 2) / 2 <= idx) ++J; // guard fp rounding
    while (J * (J + 1) / 2 > idx) --J;
    int I = idx - J * (J + 1) / 2;
    int wave = tid >> 6, lane = tid & 63, m = lane & 15, quad = lane >> 4;
    const unsigned short* zl = z + (size_t)l * NROWS * DDIM;
    int l4 = l * NROWS;
    int wr0 = I * 256 + wave * 64;

    short8 a[4][4];                           // 4 row-subtiles x 4 k-steps, resident in VGPRs
    #pragma unroll
    for (int rs = 0; rs < 4; ++rs) {
        const unsigned short* p = zl + (size_t)(wr0 + rs * 16 + m) * DDIM + quad * 8;
        #pragma unroll
        for (int kk = 0; kk < 4; ++kk) a[rs][kk] = *(const short8*)(p + kk * 32);
    }
    floatx4 rsum[4];
    #pragma unroll
    for (int rs = 0; rs < 4; ++rs) rsum[rs] = (floatx4){0.f, 0.f, 0.f, 0.f};
    float csum[16];                           // per-lane col-sum partial, col = (stg*8+cs)*16 + m
    #pragma unroll
    for (int g = 0; g < 16; ++g) csum[g] = 0.f;

    #pragma unroll                            // MUST unroll: csum[] indexed by stg (rule #20)
    for (int stg = 0; stg < 2; ++stg) {       // 2 x 128-col LDS tiles (256 cols per block)
        int cg0 = J * 256 + stg * 128;
        __syncthreads();
        #pragma unroll
        for (int i = 0; i < 8; ++i) {         // stage 128x128 bf16 (32KB), 16B chunks
            int chunk = tid + 256 * i;
            int col = chunk >> 4, off = chunk & 15;
            uint4 d = *(const uint4*)(zl + (size_t)(cg0 + col) * DDIM + off * 8);
            *(uint4*)&lds[col * LDST + off * 8] = d;
        }
        __syncthreads();
        #pragma unroll
        for (int cs = 0; cs < 8; ++cs) {      // 16-col subtiles
            int ct = cg0 + cs * 16;           // tile column base (wave-uniform)
            const unsigned short* lp = &lds[(cs * 16 + m) * LDST + quad * 8];
            short8 b0 = *(const short8*)(lp);
            short8 b1 = *(const short8*)(lp + 32);
            short8 b2 = *(const short8*)(lp + 64);
            short8 b3 = *(const short8*)(lp + 96);
            #pragma unroll
            for (int rs = 0; rs < 4; ++rs) {
                floatx4 acc = (floatx4){0.f, 0.f, 0.f, 0.f};
                acc = __builtin_amdgcn_mfma_f32_16x16x32_bf16(a[rs][0], b0, acc, 0, 0, 0);
                acc = __builtin_amdgcn_mfma_f32_16x16x32_bf16(a[rs][1], b1, acc, 0, 0, 0);
                acc = __builtin_amdgcn_mfma_f32_16x16x32_bf16(a[rs][2], b2, acc, 0, 0, 0);
                acc = __builtin_amdgcn_mfma_f32_16x16x32_bf16(a[rs][3], b3, acc, 0, 0, 0);
                int rowbase = wr0 + rs * 16;
                bool isdiag = (ct == rowbase);          // only possible when I==J
                bool ispos  = (ct == rowbase + 2048);   // only possible when J==I+8
                if (isdiag || ispos) {        // rare, wave-uniform branch
                    int c = m - (quad << 2);  // lane holds (row=rowbase+m) iff quad*4+c == m
                    if (c >= 0 && c < 4) {
                        float v = acc[c];
                        if (isdiag) diag[l4 + rowbase + m] = v;
                        else {                // sim[r, r+2048]; pos is symmetric across halves
                            pos[l4 + rowbase + m] = v;
                            pos[l4 + rowbase + m + NHALF] = v;
                        }
                    }
                }
                float t = 0.f;
                #pragma unroll
                for (int c = 0; c < 4; ++c) {
                    float e = __builtin_amdgcn_exp2f(acc[c]);
                    rsum[rs][c] += e;
                    t += e;                   // sum over this lane's 4 rows
                }
                csum[stg * 8 + cs] += t;      // accumulate col partial across rs
            }
        }
    }
    // row side: reduce across the 16 column-lanes (bits 0..3 of lane)
    #pragma unroll
    for (int off = 1; off < 16; off <<= 1)
        #pragma unroll
        for (int rs = 0; rs < 4; ++rs)
            #pragma unroll
            for (int c = 0; c < 4; ++c)
                rsum[rs][c] += __shfl_xor(rsum[rs][c], off);
    if (m == 0) {                             // lanes 0,16,32,48: rows wr0 + rs*16 + quad*4 + c
        #pragma unroll
        for (int rs = 0; rs < 4; ++rs)
            #pragma unroll
            for (int c = 0; c < 4; ++c) {
                int rg = wr0 + rs * 16 + quad * 4 + c;
                atomicAdd(&rowsum[l4 + rg], rsum[rs][c]);
            }
    }
    // col side (transpose contribution), off-diagonal tiles only — block-uniform branch
    if (I != J) {
        __syncthreads();                      // LDS tile dead; reuse as float reduce buffer
        float* cred = (float*)lds;            // [4 waves][256 cols]
        #pragma unroll
        for (int g = 0; g < 16; ++g) {        // finish reduce over the 16 rows (lane bits 4,5)
            float v = csum[g];
            v += __shfl_xor(v, 16);
            v += __shfl_xor(v, 32);
            if (quad == 0) cred[wave * 256 + g * 16 + m] = v;
        }
        __syncthreads();
        float s = cred[tid] + cred[tid + 256] + cred[tid + 512] + cred[tid + 768];
        atomicAdd(&rowsum[l4 + J * 256 + tid], s);  // 256 atomics/block (LDS pre-reduced)
    }
}

// ---------------- kernel 3: per-row loss; last block finishes the scalar (no k_final) ------
__global__ __launch_bounds__(256) void k_loss(const float* __restrict__ jv,
                                              const float* __restrict__ rowsum,
                                              const float* __restrict__ diag,
                                              const float* __restrict__ pos,
                                              float* __restrict__ wsf,
                                              float* __restrict__ out) {
    __shared__ float sred[256];
    int tid = threadIdx.x;
    int r = blockIdx.x * 256 + tid;           // 64 blocks x 256 = 16384 rows
    int n = r & 4095;
    float denom = rowsum[r] - __builtin_amdgcn_exp2f(diag[r]);  // exact: same fp32 value
    float contrib = LN2 * (__builtin_amdgcn_logf(denom) - pos[r]); // logf = v_log_f32 = log2
    float local = contrib * jv[n & (NHALF - 1)];
    sred[tid] = local; __syncthreads();
    for (int off = 128; off > 0; off >>= 1) {
        if (tid < off) sred[tid] += sred[tid + off];
        __syncthreads();
    }
    if (tid == 0) {
        atomicAdd(&wsf[0], sred[0]);
        __threadfence();                      // order loss-add before counter-add
        unsigned c = atomicAdd((unsigned*)&wsf[2], 1u);
        if (c == 63) {                        // 64th (last) block: finalize
            float tot = atomicAdd(&wsf[0], 0.f);   // device-scope coherent read
            out[0] = tot / (2.f * wsf[1]);
        }
    }
}

extern "C" void kernel_launch(void* const* d_in, const int* in_sizes, int n_in,
                              void* d_out, int out_size, void* d_ws, size_t ws_size,
                              hipStream_t stream) {
    const float* emb_i = (const float*)d_in[0];
    const float* emb_j = (const float*)d_in[1];
    const float* jv    = (const float*)d_in[2];
    float* wsf    = (float*)d_ws;
    float* rowsum = wsf + WS_ROWSUM_OFF;
    float* diag   = wsf + WS_DIAG_OFF;
    float* pos    = wsf + WS_POS_OFF;
    unsigned short* z = (unsigned short*)((char*)d_ws + WS_Z_BYTE_OFF);
    float* out = (float*)d_out;

    k_norm <<<4097, 256, 0, stream>>>(emb_i, emb_j, jv, wsf, z);
    k_sim  <<<544,  256, 0, stream>>>(z, rowsum, diag, pos);   // 4 l x 136 upper-tri tiles
    k_loss <<<64,   256, 0, stream>>>(jv, rowsum, diag, pos, wsf, out);
}

// Round 3
// 87.649 us; speedup vs baseline: 1.4451x; 1.2177x over previous
//
#include <hip/hip_runtime.h>
#include <hip/hip_bf16.h>

typedef __attribute__((ext_vector_type(8))) short short8;
typedef __attribute__((ext_vector_type(4))) float floatx4;

#define NROWS 4096
#define NHALF 2048
#define DDIM  128
#define LDST  136                 // LDS row stride in ushorts (128 + 8 pad -> 272B, 2-way = free)
#define SQRT_SCALE 2.6857914f     // sqrt(1/(0.2*ln2)) ; dot of stored z == (sim/T)*log2(e)
#define LN2 0.69314718056f

// ws float layout: [0]=loss acc, [1]=all_num, [2]=k_loss completion counter,
// rowsum [64, 64+16384), diag [16448, +16384), pos [32832, +16384)
#define WS_ROWSUM_OFF 64
#define WS_DIAG_OFF   16448
#define WS_POS_OFF    32832
#define WS_Z_BYTE_OFF 196864      // (64+3*16384)*4, 16B aligned

__device__ inline unsigned short f2bf(float f) {
    unsigned u = __builtin_bit_cast(unsigned, f);
    u += 0x7fffu + ((u >> 16) & 1u);          // RNE
    return (unsigned short)(u >> 16);
}

// ---------------- kernel 1: normalize + scale + cast to bf16; zero accumulators; all_num ----
__global__ __launch_bounds__(256) void k_norm(const float* __restrict__ emb_i,
                                              const float* __restrict__ emb_j,
                                              const float* __restrict__ jv,
                                              float* __restrict__ wsf,
                                              unsigned short* __restrict__ z) {
    int bx = blockIdx.x, tid = threadIdx.x;
    if (bx == 4096) {                         // all_num = sum(joint_valid)
        __shared__ float sred[256];
        float s = 0.f;
        #pragma unroll
        for (int i = 0; i < 8; ++i) s += jv[tid + 256 * i];
        sred[tid] = s; __syncthreads();
        for (int off = 128; off > 0; off >>= 1) {
            if (tid < off) sred[tid] += sred[tid + off];
            __syncthreads();
        }
        if (tid == 0) wsf[1] = sred[0];
        return;
    }
    int gid = bx * 256 + tid;                 // zero loss acc + counter + rowsum (ws poisoned each call)
    if (gid == 0) { wsf[0] = 0.f; *(unsigned*)&wsf[2] = 0u; }
    if (gid >= WS_ROWSUM_OFF && gid < WS_ROWSUM_OFF + 16384) wsf[gid] = 0.f;

    int wave = tid >> 6, lane = tid & 63;
    int r = bx * 4 + wave;                    // global row 0..16383
    int l = r >> 12, n = r & 4095;
    const float* src = (n < NHALF) ? (emb_i + ((size_t)l * NHALF + n) * DDIM)
                                   : (emb_j + ((size_t)l * NHALF + (n - NHALF)) * DDIM);
    float2 v = *(const float2*)(src + lane * 2);
    float ss = v.x * v.x + v.y * v.y;
    #pragma unroll
    for (int off = 1; off < 64; off <<= 1) ss += __shfl_xor(ss, off);
    float inv = SQRT_SCALE / fmaxf(sqrtf(ss), 1e-12f);
    unsigned pack = ((unsigned)f2bf(v.y * inv) << 16) | (unsigned)f2bf(v.x * inv);
    *(unsigned*)(z + (size_t)r * DDIM + lane * 2) = pack;
}

// ---------------- kernel 2: SYMMETRIC fused sim GEMM + exp2 row/col sums + diag/pos ---------
// R2 post-mortem: 40.5us at Occupancy 7%, MfmaUtil 7.7% -> latency-bound at 2 waves/SIMD
// (VGPR 212) with 544 fat blocks (2x residency rounds, 50% tail).
// R3: 128x128 tiles, 32 rows/wave -> live state ~85 VGPR (a=32, rsum=8, csum=8) so the
// allocator lands <=128 -> 4 waves/SIMD, 4 blocks/CU; 2112 small blocks -> fine-grain tail.
// Upper-triangle of 32x32 tile grid: idx = J*(J+1)/2 + I, I<=J, 528 tiles per l.
__global__ __launch_bounds__(256) void k_sim(const unsigned short* __restrict__ z,
                                             float* __restrict__ rowsum,
                                             float* __restrict__ diag,
                                             float* __restrict__ pos) {
    __shared__ __align__(16) unsigned short lds[128 * LDST];
    int bx = blockIdx.x, tid = threadIdx.x;
    int l = bx & 3, idx = bx >> 2;            // idx in [0,528)
    int J = (int)((sqrtf(8.f * (float)idx + 1.f) - 1.f) * 0.5f);
    while ((J + 1) * (J + 2) / 2 <= idx) ++J; // guard fp rounding
    while (J * (J + 1) / 2 > idx) --J;
    int I = idx - J * (J + 1) / 2;
    int wave = tid >> 6, lane = tid & 63, m = lane & 15, quad = lane >> 4;
    const unsigned short* zl = z + (size_t)l * NROWS * DDIM;
    int l4 = l * NROWS;
    int wr0 = I * 128 + wave * 32;            // 32 rows per wave
    int cg0 = J * 128;

    short8 a[2][4];                           // 2 row-subtiles x 4 k-steps
    #pragma unroll
    for (int rs = 0; rs < 2; ++rs) {
        const unsigned short* p = zl + (size_t)(wr0 + rs * 16 + m) * DDIM + quad * 8;
        #pragma unroll
        for (int kk = 0; kk < 4; ++kk) a[rs][kk] = *(const short8*)(p + kk * 32);
    }
    floatx4 rsum[2];
    #pragma unroll
    for (int rs = 0; rs < 2; ++rs) rsum[rs] = (floatx4){0.f, 0.f, 0.f, 0.f};
    float csum[8];                            // per-lane col partial, col = cs*16 + m
    #pragma unroll
    for (int g = 0; g < 8; ++g) csum[g] = 0.f;

    // stage 128x128 bf16 B-tile (cols cg0..cg0+127), 16B chunks, coalesced
    #pragma unroll
    for (int i = 0; i < 8; ++i) {
        int chunk = tid + 256 * i;
        int col = chunk >> 4, off = chunk & 15;
        uint4 d = *(const uint4*)(zl + (size_t)(cg0 + col) * DDIM + off * 8);
        *(uint4*)&lds[col * LDST + off * 8] = d;
    }
    __syncthreads();

    #pragma unroll
    for (int cs = 0; cs < 8; ++cs) {          // 16-col subtiles
        int ct = cg0 + cs * 16;               // tile column base (wave-uniform)
        const unsigned short* lp = &lds[(cs * 16 + m) * LDST + quad * 8];
        short8 b0 = *(const short8*)(lp);
        short8 b1 = *(const short8*)(lp + 32);
        short8 b2 = *(const short8*)(lp + 64);
        short8 b3 = *(const short8*)(lp + 96);
        #pragma unroll
        for (int rs = 0; rs < 2; ++rs) {
            floatx4 acc = (floatx4){0.f, 0.f, 0.f, 0.f};
            acc = __builtin_amdgcn_mfma_f32_16x16x32_bf16(a[rs][0], b0, acc, 0, 0, 0);
            acc = __builtin_amdgcn_mfma_f32_16x16x32_bf16(a[rs][1], b1, acc, 0, 0, 0);
            acc = __builtin_amdgcn_mfma_f32_16x16x32_bf16(a[rs][2], b2, acc, 0, 0, 0);
            acc = __builtin_amdgcn_mfma_f32_16x16x32_bf16(a[rs][3], b3, acc, 0, 0, 0);
            int rowbase = wr0 + rs * 16;
            bool isdiag = (ct == rowbase);          // only when I==J, cs == wave*2+rs
            bool ispos  = (ct == rowbase + 2048);   // only when J==I+16, cs == wave*2+rs
            if (isdiag || ispos) {            // rare, wave-uniform branch
                int c = m - (quad << 2);      // acc[c] holds sim[rowbase+quad*4+c][ct+m]
                if (c >= 0 && c < 4) {        // -> diagonal element iff quad*4+c == m
                    float v = acc[c];
                    if (isdiag) diag[l4 + rowbase + m] = v;
                    else {                    // sim[r, r+2048]; pos symmetric across halves
                        pos[l4 + rowbase + m] = v;
                        pos[l4 + rowbase + m + NHALF] = v;
                    }
                }
            }
            float t = 0.f;
            #pragma unroll
            for (int c = 0; c < 4; ++c) {
                float e = __builtin_amdgcn_exp2f(acc[c]);
                rsum[rs][c] += e;
                t += e;                       // sum over this lane's 4 rows
            }
            csum[cs] += t;                    // accumulate col partial across rs
        }
    }
    // row side: reduce across the 16 column-lanes (bits 0..3 of lane)
    #pragma unroll
    for (int off = 1; off < 16; off <<= 1)
        #pragma unroll
        for (int rs = 0; rs < 2; ++rs)
            #pragma unroll
            for (int c = 0; c < 4; ++c)
                rsum[rs][c] += __shfl_xor(rsum[rs][c], off);
    if (m == 0) {                             // lanes 0,16,32,48: rows wr0 + rs*16 + quad*4 + c
        #pragma unroll
        for (int rs = 0; rs < 2; ++rs)
            #pragma unroll
            for (int c = 0; c < 4; ++c) {
                int rg = wr0 + rs * 16 + quad * 4 + c;
                atomicAdd(&rowsum[l4 + rg], rsum[rs][c]);
            }
    }
    // col side (transpose contribution), off-diagonal tiles only — block-uniform branch
    if (I != J) {
        __syncthreads();                      // LDS tile dead; reuse as float reduce buffer
        float* cred = (float*)lds;            // [4 waves][128 cols]
        #pragma unroll
        for (int g = 0; g < 8; ++g) {         // finish reduce over the 16 rows (lane bits 4,5)
            float v = csum[g];
            v += __shfl_xor(v, 16);
            v += __shfl_xor(v, 32);
            if (quad == 0) cred[wave * 128 + g * 16 + m] = v;
        }
        __syncthreads();
        if (tid < 128) {
            float s = cred[tid] + cred[tid + 128] + cred[tid + 256] + cred[tid + 384];
            atomicAdd(&rowsum[l4 + cg0 + tid], s);  // 128 atomics/block (LDS pre-reduced)
        }
    }
}

// ---------------- kernel 3: per-row loss; last block finishes the scalar (no k_final) ------
__global__ __launch_bounds__(256) void k_loss(const float* __restrict__ jv,
                                              const float* __restrict__ rowsum,
                                              const float* __restrict__ diag,
                                              const float* __restrict__ pos,
                                              float* __restrict__ wsf,
                                              float* __restrict__ out) {
    __shared__ float sred[256];
    int tid = threadIdx.x;
    int r = blockIdx.x * 256 + tid;           // 64 blocks x 256 = 16384 rows
    int n = r & 4095;
    float denom = rowsum[r] - __builtin_amdgcn_exp2f(diag[r]);  // exact: same fp32 value
    float contrib = LN2 * (__builtin_amdgcn_logf(denom) - pos[r]); // logf = v_log_f32 = log2
    float local = contrib * jv[n & (NHALF - 1)];
    sred[tid] = local; __syncthreads();
    for (int off = 128; off > 0; off >>= 1) {
        if (tid < off) sred[tid] += sred[tid + off];
        __syncthreads();
    }
    if (tid == 0) {
        atomicAdd(&wsf[0], sred[0]);
        __threadfence();                      // order loss-add before counter-add
        unsigned c = atomicAdd((unsigned*)&wsf[2], 1u);
        if (c == 63) {                        // 64th (last) block: finalize
            float tot = atomicAdd(&wsf[0], 0.f);   // device-scope coherent read
            out[0] = tot / (2.f * wsf[1]);
        }
    }
}

extern "C" void kernel_launch(void* const* d_in, const int* in_sizes, int n_in,
                              void* d_out, int out_size, void* d_ws, size_t ws_size,
                              hipStream_t stream) {
    const float* emb_i = (const float*)d_in[0];
    const float* emb_j = (const float*)d_in[1];
    const float* jv    = (const float*)d_in[2];
    float* wsf    = (float*)d_ws;
    float* rowsum = wsf + WS_ROWSUM_OFF;
    float* diag   = wsf + WS_DIAG_OFF;
    float* pos    = wsf + WS_POS_OFF;
    unsigned short* z = (unsigned short*)((char*)d_ws + WS_Z_BYTE_OFF);
    float* out = (float*)d_out;

    k_norm <<<4097, 256, 0, stream>>>(emb_i, emb_j, jv, wsf, z);
    k_sim  <<<2112, 256, 0, stream>>>(z, rowsum, diag, pos);   // 4 l x 528 upper-tri 128x128
    k_loss <<<64,   256, 0, stream>>>(jv, rowsum, diag, pos, wsf, out);
}